// Round 11
// baseline (1277.525 us; speedup 1.0000x reference)
//
#include <hip/hip_runtime.h>

#define BATCH 8
#define NPTS 8192
#define NCH 64
#define NPOINT 1024
#define NSAMPLE 32
#define G 16  // groups per MLP block

typedef float f4 __attribute__((ext_vector_type(4)));
typedef float f2 __attribute__((ext_vector_type(2)));
typedef _Float16 h8 __attribute__((ext_vector_type(8)));

// gfx950 VOP3P packed fp32: only pk_add/pk_mul/pk_fma exist (no pk_min/max).
// __builtin_elementwise_* on f2 scalarizes the whole chain; force VOP3P with
// inline asm. Each lane computes two independent IEEE ops — bit-identical to
// the scalar pair.
__device__ __forceinline__ f2 pk_sub(f2 a, f2 b) {
  f2 d;
  asm("v_pk_add_f32 %0, %1, %2 neg_lo:[0,1] neg_hi:[0,1]"
      : "=v"(d) : "v"(a), "v"(b));
  return d;
}
__device__ __forceinline__ f2 pk_mul(f2 a, f2 b) {
  f2 d;
  asm("v_pk_mul_f32 %0, %1, %2" : "=v"(d) : "v"(a), "v"(b));
  return d;
}
__device__ __forceinline__ f2 pk_add(f2 a, f2 b) {
  f2 d;
  asm("v_pk_add_f32 %0, %1, %2" : "=v"(d) : "v"(a), "v"(b));
  return d;
}

// DPP-based u64 max step: merge with the value DPP-shifted across lanes.
template <int CTRL>
__device__ __forceinline__ unsigned long long dpp_max_u64(unsigned long long k) {
  int lo = (int)(unsigned int)k;
  int hi = (int)(unsigned int)(k >> 32);
  int slo = __builtin_amdgcn_update_dpp(lo, lo, CTRL, 0xf, 0xf, false);
  int shi = __builtin_amdgcn_update_dpp(hi, hi, CTRL, 0xf, 0xf, false);
  unsigned long long s =
      ((unsigned long long)(unsigned int)shi << 32) | (unsigned int)slo;
  return (s > k) ? s : k;
}

// ---------------------------------------------------------------------------
// Furthest point sampling — R6 structure + forced-VOP3P distance update.
// 256 threads (4 waves, 1/SIMD) is the empirical optimum of this family
// (R4 1024t=1322, R6 256t=1042, R7 512t=1194).
// ---------------------------------------------------------------------------
__global__ __launch_bounds__(256) void fps_kernel(const float* __restrict__ xyz,
                                                  float* __restrict__ newxyz) {
  const int b = blockIdx.x;
  const int tid = threadIdx.x;
  const int lane = tid & 63;
  const int wid = tid >> 6;  // 0..3
  const float* xb = xyz + (size_t)b * NPTS * 3;

  __shared__ float px_l[NPTS], py_l[NPTS], pz_l[NPTS];        // 96 KB SoA
  __shared__ __align__(16) unsigned long long pke[2][4][4];   // key, xy, z, pad
  __shared__ unsigned short winidx[NPOINT];

  for (int p = tid; p < NPTS; p += 256) {
    px_l[p] = xb[p * 3 + 0];
    py_l[p] = xb[p * 3 + 1];
    pz_l[p] = xb[p * 3 + 2];
  }
  __syncthreads();

  f2 pxv[16], pyv[16], pzv[16], mindv[16];
#pragma unroll
  for (int j = 0; j < 16; ++j) {
    int p = 2 * tid + 512 * j;
    pxv[j] = *(const f2*)&px_l[p];
    pyv[j] = *(const f2*)&py_l[p];
    pzv[j] = *(const f2*)&pz_l[p];
    mindv[j] = f2{1e10f, 1e10f};
  }
  float qx = px_l[0], qy = py_l[0], qz = pz_l[0];  // pivot = point 0

  for (int i = 1; i < NPOINT; ++i) {
#pragma clang fp contract(off)
    const int par = i & 1;
    f2 qx2 = f2{qx, qx}, qy2 = f2{qy, qy}, qz2 = f2{qz, qz};

    // distance update: 8 VOP3P + 2 scalar min + (tree) max per slot.
    // exact ref order/rounding: d = (dx*dx + dy*dy) + dz*dz, then min.
    f2 tmax;
#pragma unroll
    for (int j = 0; j < 16; ++j) {
      f2 dx = pk_sub(pxv[j], qx2);
      f2 dy = pk_sub(pyv[j], qy2);
      f2 dz = pk_sub(pzv[j], qz2);
      f2 d = pk_add(pk_add(pk_mul(dx, dx), pk_mul(dy, dy)), pk_mul(dz, dz));
      f2 m = __builtin_elementwise_min(mindv[j], d);
      mindv[j] = m;
      tmax = (j == 0) ? m : __builtin_elementwise_max(tmax, m);
    }
    float lmax = fmaxf(tmax.x, tmax.y);

    // thread-local lowest global index achieving lmax
    // global idx = 2*tid + 512*j + k; scan j desc, y(k=1) then x(k=0)
    int c = 0;
#pragma unroll
    for (int j = 15; j >= 0; --j) {
      if (mindv[j].y == lmax) c = 2 * j + 1;
      if (mindv[j].x == lmax) c = 2 * j;
    }
    unsigned int gidx = (unsigned int)(2 * tid + ((c >> 1) << 9) + (c & 1));
    unsigned long long key =
        ((unsigned long long)__float_as_uint(lmax) << 32) |
        (unsigned long long)(~gidx);

    key = dpp_max_u64<0x111>(key);  // row_shr:1
    key = dpp_max_u64<0x112>(key);  // row_shr:2
    key = dpp_max_u64<0x114>(key);  // row_shr:4
    key = dpp_max_u64<0x118>(key);  // row_shr:8
    key = dpp_max_u64<0x142>(key);  // row_bcast:15
    key = dpp_max_u64<0x143>(key);  // row_bcast:31

    if (lane == 63) {
      unsigned int widx = ~(unsigned int)key;
      float wx = px_l[widx], wy = py_l[widx], wz = pz_l[widx];
      ulonglong2 e0;
      e0.x = key;
      e0.y = ((unsigned long long)__float_as_uint(wy) << 32) |
             (unsigned long long)__float_as_uint(wx);
      *(ulonglong2*)&pke[par][wid][0] = e0;
      pke[par][wid][2] = (unsigned long long)__float_as_uint(wz);
    }
    __syncthreads();

    const ulonglong2* ew = (const ulonglong2*)&pke[par][0][0];
    ulonglong2 m0 = ew[0];
    unsigned long long bz = ew[1].x;
#pragma unroll
    for (int w = 1; w < 4; ++w) {
      ulonglong2 t = ew[2 * w];
      unsigned long long tz = ew[2 * w + 1].x;
      if (t.x > m0.x) { m0 = t; bz = tz; }
    }
    qx = __uint_as_float((unsigned int)m0.y);
    qy = __uint_as_float((unsigned int)(m0.y >> 32));
    qz = __uint_as_float((unsigned int)bz);
    if (tid == 0) winidx[i] = (unsigned short)(~(unsigned int)m0.x);
  }

  __syncthreads();
  for (int t = tid; t < NPOINT; t += 256) {
    const int idx = (t == 0) ? 0 : (int)winidx[t];
    float* op = newxyz + b * (NPOINT * 3) + t * 3;
    op[0] = px_l[idx];
    op[1] = py_l[idx];
    op[2] = pz_l[idx];
  }
}

// ---------------------------------------------------------------------------
// Ball query: one wave per (b, s) center. Unchanged (exact fp32).
// ---------------------------------------------------------------------------
__global__ __launch_bounds__(256) void ball_kernel(const float* __restrict__ xyz,
                                                   const float* __restrict__ newxyz,
                                                   int* __restrict__ idxout) {
  const int lane = threadIdx.x & 63;
  const int pair = blockIdx.x * 4 + (threadIdx.x >> 6);
  const int b = pair >> 10;
  const float cx = newxyz[pair * 3 + 0];
  const float cy = newxyz[pair * 3 + 1];
  const float cz = newxyz[pair * 3 + 2];
  const float* xb = xyz + (size_t)b * NPTS * 3;
  int* op = idxout + pair * NSAMPLE;

  int cnt = 0;
  int first = 0;
  for (int base = 0; base < NPTS && cnt < NSAMPLE; base += 64) {
    const int p = base + lane;
    const float* pp = xb + p * 3;
    float dx = __fsub_rn(cx, pp[0]);
    float dy = __fsub_rn(cy, pp[1]);
    float dz = __fsub_rn(cz, pp[2]);
    float d2 = __fadd_rn(__fadd_rn(__fmul_rn(dx, dx), __fmul_rn(dy, dy)),
                         __fmul_rn(dz, dz));
    bool pred = d2 < 0.04f;
    unsigned long long m = __ballot(pred);
    if (cnt == 0 && m) first = base + __builtin_ctzll(m);
    int rank = cnt + (int)__popcll(m & ((1ull << lane) - 1ull));
    if (pred && rank < NSAMPLE) op[rank] = p;
    cnt += (int)__popcll(m);
  }
  if (cnt < NSAMPLE) {
    for (int r = cnt + lane; r < NSAMPLE; r += 64) op[r] = first;
  }
}

// ---------------------------------------------------------------------------
// Group + 3-layer MLP + max-pool via f16 MFMA. G=16 groups/block, grid 512.
// Unchanged from R10 (MLP tail ~100 us; weights register-resident as
// B-fragments, layouts HW-verified m89/m120, fp32 accumulate).
// ---------------------------------------------------------------------------
__global__ __launch_bounds__(256) void group_mlp_kernel(
    const float* __restrict__ xyz, const float* __restrict__ feat,
    const float* __restrict__ w0, const float* __restrict__ s0, const float* __restrict__ b0,
    const float* __restrict__ w1, const float* __restrict__ s1, const float* __restrict__ b1,
    const float* __restrict__ w2, const float* __restrict__ s2, const float* __restrict__ b2,
    const int* __restrict__ idxin, const float* __restrict__ newxyz,
    float* __restrict__ outf) {
  __shared__ _Float16 x0[32 * 104];  // layer1 input, K-padded to 96
  __shared__ _Float16 x1[32 * 72];   // layer2 input
  __shared__ _Float16 x2[32 * 72];   // layer3 input
  __shared__ float obuf[128 * G];

  const int tid = threadIdx.x;
  const int lane = tid & 63;
  const int wv = tid >> 6;       // wave 0..3
  const int qd = lane >> 4;      // quad 0..3
  const int col = lane & 15;
  const int pair0 = blockIdx.x * G;
  const int b = pair0 >> 10;
  const int sbase = pair0 & 1023;

  // ---- build register-resident B-fragments (once per block) ----
  h8 bf1[3], bf2[2], bf3[2][2];
  {
    const int o1 = wv * 16 + col;  // L1/L2 channel for this lane
#pragma unroll
    for (int t = 0; t < 3; ++t) {
#pragma unroll
      for (int j = 0; j < 8; ++j) {
        int kp = t * 32 + qd * 8 + j;  // permuted K index
        float v = 0.f;
        if (kp < 64) v = w0[o1 * 67 + 3 + kp];
        else if (kp < 67) v = w0[o1 * 67 + (kp - 64)];
        bf1[t][j] = (_Float16)v;
      }
    }
#pragma unroll
    for (int t = 0; t < 2; ++t) {
#pragma unroll
      for (int j = 0; j < 8; ++j) {
        int k = t * 32 + qd * 8 + j;
        bf2[t][j] = (_Float16)w1[o1 * 64 + k];
      }
    }
#pragma unroll
    for (int u = 0; u < 2; ++u) {
      const int o3 = (wv + 4 * u) * 16 + col;
#pragma unroll
      for (int t = 0; t < 2; ++t) {
#pragma unroll
        for (int j = 0; j < 8; ++j) {
          int k = t * 32 + qd * 8 + j;
          bf3[u][t][j] = (_Float16)w2[o3 * 64 + k];
        }
      }
    }
  }
  const int o12 = wv * 16 + col;
  const float sA = s0[o12], bA = b0[o12];
  const float sB = s1[o12], bB = b1[o12];
  const float sC0 = s2[o12], bC0 = b2[o12];
  const float sC1 = s2[o12 + 64], bC1 = b2[o12 + 64];

  for (int t = tid; t < 32 * 40; t += 256) {
    x0[(t / 40) * 104 + 64 + (t % 40)] = (_Float16)0.f;
  }

  const int gn = tid >> 3, gk = tid & 7;

  f4 pf0, pf1;
  float pxr = 0.f, pyr = 0.f, pzr = 0.f, cxr = 0.f, cyr = 0.f, czr = 0.f;
  {
    const int pid = idxin[pair0 * NSAMPLE + gn];
    const float* fr = feat + ((size_t)(b * NPTS) + pid) * NCH + gk * 8;
    pf0 = *(const f4*)fr;
    pf1 = *(const f4*)(fr + 4);
    if (gk == 0) {
      const float* pr = xyz + ((size_t)(b * NPTS) + pid) * 3;
      pxr = pr[0]; pyr = pr[1]; pzr = pr[2];
      cxr = newxyz[pair0 * 3 + 0];
      cyr = newxyz[pair0 * 3 + 1];
      czr = newxyz[pair0 * 3 + 2];
    }
  }

  for (int g = 0; g < G; ++g) {
    {
      h8 hv;
#pragma unroll
      for (int q = 0; q < 4; ++q) {
        hv[q] = (_Float16)pf0[q];
        hv[4 + q] = (_Float16)pf1[q];
      }
      *(h8*)&x0[gn * 104 + gk * 8] = hv;
      if (gk == 0) {
        x0[gn * 104 + 64] = (_Float16)(pxr - cxr);
        x0[gn * 104 + 65] = (_Float16)(pyr - cyr);
        x0[gn * 104 + 66] = (_Float16)(pzr - czr);
      }
    }
    __syncthreads();  // bar A: x0 ready

    if (g + 1 < G) {
      const int pairg = pair0 + g + 1;
      const int pid = idxin[pairg * NSAMPLE + gn];
      const float* fr = feat + ((size_t)(b * NPTS) + pid) * NCH + gk * 8;
      pf0 = *(const f4*)fr;
      pf1 = *(const f4*)(fr + 4);
      if (gk == 0) {
        const float* pr = xyz + ((size_t)(b * NPTS) + pid) * 3;
        pxr = pr[0]; pyr = pr[1]; pzr = pr[2];
        cxr = newxyz[pairg * 3 + 0];
        cyr = newxyz[pairg * 3 + 1];
        czr = newxyz[pairg * 3 + 2];
      }
    }

    // ---- layer 1 ----
    {
      f4 a0 = {0.f, 0.f, 0.f, 0.f}, a1 = a0;
#pragma unroll
      for (int t = 0; t < 3; ++t) {
        h8 fa0 = *(const h8*)&x0[col * 104 + t * 32 + qd * 8];
        h8 fa1 = *(const h8*)&x0[(16 + col) * 104 + t * 32 + qd * 8];
        a0 = __builtin_amdgcn_mfma_f32_16x16x32_f16(fa0, bf1[t], a0, 0, 0, 0);
        a1 = __builtin_amdgcn_mfma_f32_16x16x32_f16(fa1, bf1[t], a1, 0, 0, 0);
      }
#pragma unroll
      for (int r = 0; r < 4; ++r) {
        float v0 = fmaxf(fmaf(a0[r], sA, bA), 0.f);
        float v1 = fmaxf(fmaf(a1[r], sA, bA), 0.f);
        x1[(qd * 4 + r) * 72 + o12] = (_Float16)v0;
        x1[(16 + qd * 4 + r) * 72 + o12] = (_Float16)v1;
      }
    }
    __syncthreads();  // bar B: x1 ready

    // ---- layer 2 ----
    {
      f4 a0 = {0.f, 0.f, 0.f, 0.f}, a1 = a0;
#pragma unroll
      for (int t = 0; t < 2; ++t) {
        h8 fa0 = *(const h8*)&x1[col * 72 + t * 32 + qd * 8];
        h8 fa1 = *(const h8*)&x1[(16 + col) * 72 + t * 32 + qd * 8];
        a0 = __builtin_amdgcn_mfma_f32_16x16x32_f16(fa0, bf2[t], a0, 0, 0, 0);
        a1 = __builtin_amdgcn_mfma_f32_16x16x32_f16(fa1, bf2[t], a1, 0, 0, 0);
      }
#pragma unroll
      for (int r = 0; r < 4; ++r) {
        float v0 = fmaxf(fmaf(a0[r], sB, bB), 0.f);
        float v1 = fmaxf(fmaf(a1[r], sB, bB), 0.f);
        x2[(qd * 4 + r) * 72 + o12] = (_Float16)v0;
        x2[(16 + qd * 4 + r) * 72 + o12] = (_Float16)v1;
      }
    }
    __syncthreads();  // bar C: x2 ready

    // ---- layer 3 + max-pool ----
    {
      f4 c00 = {0.f, 0.f, 0.f, 0.f}, c01 = c00, c10 = c00, c11 = c00;
#pragma unroll
      for (int t = 0; t < 2; ++t) {
        h8 fa0 = *(const h8*)&x2[col * 72 + t * 32 + qd * 8];
        h8 fa1 = *(const h8*)&x2[(16 + col) * 72 + t * 32 + qd * 8];
        c00 = __builtin_amdgcn_mfma_f32_16x16x32_f16(fa0, bf3[0][t], c00, 0, 0, 0);
        c01 = __builtin_amdgcn_mfma_f32_16x16x32_f16(fa1, bf3[0][t], c01, 0, 0, 0);
        c10 = __builtin_amdgcn_mfma_f32_16x16x32_f16(fa0, bf3[1][t], c10, 0, 0, 0);
        c11 = __builtin_amdgcn_mfma_f32_16x16x32_f16(fa1, bf3[1][t], c11, 0, 0, 0);
      }
      float mx0 = 0.f, mx1 = 0.f;  // relu output >= 0
#pragma unroll
      for (int r = 0; r < 4; ++r) {
        mx0 = fmaxf(mx0, fmaxf(fmaf(c00[r], sC0, bC0), 0.f));
        mx0 = fmaxf(mx0, fmaxf(fmaf(c01[r], sC0, bC0), 0.f));
        mx1 = fmaxf(mx1, fmaxf(fmaf(c10[r], sC1, bC1), 0.f));
        mx1 = fmaxf(mx1, fmaxf(fmaf(c11[r], sC1, bC1), 0.f));
      }
      mx0 = fmaxf(mx0, __shfl_xor(mx0, 16));
      mx0 = fmaxf(mx0, __shfl_xor(mx0, 32));
      mx1 = fmaxf(mx1, __shfl_xor(mx1, 16));
      mx1 = fmaxf(mx1, __shfl_xor(mx1, 32));
      if (lane < 16) {
        obuf[o12 * G + g] = mx0;
        obuf[(o12 + 64) * G + g] = mx1;
      }
    }
  }

  __syncthreads();
  {
    const int ch = tid >> 1, hb = (tid & 1) * 8;
    f4 v0 = *(const f4*)&obuf[ch * G + hb];
    f4 v1 = *(const f4*)&obuf[ch * G + hb + 4];
    float* dst = &outf[((size_t)(b * 128 + ch)) * 1024 + sbase + hb];
    *(f4*)dst = v0;
    *(f4*)(dst + 4) = v1;
  }
}

extern "C" void kernel_launch(void* const* d_in, const int* in_sizes, int n_in,
                              void* d_out, int out_size, void* d_ws, size_t ws_size,
                              hipStream_t stream) {
  const float* xyz = (const float*)d_in[0];
  const float* feat = (const float*)d_in[1];
  const float* w0 = (const float*)d_in[2];
  const float* s0 = (const float*)d_in[3];
  const float* b0 = (const float*)d_in[4];
  const float* w1 = (const float*)d_in[5];
  const float* s1 = (const float*)d_in[6];
  const float* b1 = (const float*)d_in[7];
  const float* w2 = (const float*)d_in[8];
  const float* s2 = (const float*)d_in[9];
  const float* b2 = (const float*)d_in[10];

  float* newxyz = (float*)d_out;                    // (8,1024,3)
  float* outf = (float*)d_out + BATCH * NPOINT * 3; // (8,128,1024)
  int* idxws = (int*)d_ws;                          // (8*1024, 32) ints = 1 MB

  fps_kernel<<<BATCH, 256, 0, stream>>>(xyz, newxyz);
  ball_kernel<<<(BATCH * NPOINT) / 4, 256, 0, stream>>>(xyz, newxyz, idxws);
  group_mlp_kernel<<<(BATCH * NPOINT) / G, 256, 0, stream>>>(
      xyz, feat, w0, s0, b0, w1, s1, b1, w2, s2, b2, idxws, newxyz, outf);
}

// Round 12
// 1073.403 us; speedup vs baseline: 1.1902x; 1.1902x over previous
//
#include <hip/hip_runtime.h>

#define BATCH 8
#define NPTS 8192
#define NCH 64
#define NPOINT 1024
#define NSAMPLE 32
#define G 16  // groups per MLP block

typedef float f4 __attribute__((ext_vector_type(4)));
typedef float f2 __attribute__((ext_vector_type(2)));
typedef _Float16 h8 __attribute__((ext_vector_type(8)));

// DPP-based u64 max step: merge with the value DPP-shifted across lanes.
template <int CTRL>
__device__ __forceinline__ unsigned long long dpp_max_u64(unsigned long long k) {
  int lo = (int)(unsigned int)k;
  int hi = (int)(unsigned int)(k >> 32);
  int slo = __builtin_amdgcn_update_dpp(lo, lo, CTRL, 0xf, 0xf, false);
  int shi = __builtin_amdgcn_update_dpp(hi, hi, CTRL, 0xf, 0xf, false);
  unsigned long long s =
      ((unsigned long long)(unsigned int)shi << 32) | (unsigned int)slo;
  return (s > k) ? s : k;
}

// ---------------------------------------------------------------------------
// Furthest point sampling — R6/R10 structure with a slimmed cross-wave merge.
// R11 post-mortem: inline-asm pk ops regressed (opaque asm defeats folding);
// reverted. New: the old merge read 8x ds_read_b128/thread ({key,coords}
// entries) = ~380 cyc serialized LDS on the critical path. Now lane 63 posts
// ONLY the 8-byte key; merge = 2x ds_read_b128 + 3 u64 selects; pivot coords
// fetched via 3 broadcast ds_read_b32 after the winner is known. Semantics
// unchanged (key = (mind<<32)|~idx, u64 max -> lowest index on ties).
// 256 threads (4 waves, 1/SIMD): empirical optimum (R4/R6/R7 bracket).
// ---------------------------------------------------------------------------
__global__ __launch_bounds__(256) void fps_kernel(const float* __restrict__ xyz,
                                                  float* __restrict__ newxyz) {
  const int b = blockIdx.x;
  const int tid = threadIdx.x;
  const int lane = tid & 63;
  const int wid = tid >> 6;  // 0..3
  const float* xb = xyz + (size_t)b * NPTS * 3;

  __shared__ float px_l[NPTS], py_l[NPTS], pz_l[NPTS];   // 96 KB SoA
  __shared__ __align__(16) unsigned long long pk2[2][4]; // key per wave
  __shared__ unsigned short winidx[NPOINT];

  // coalesced global -> LDS staging
  for (int p = tid; p < NPTS; p += 256) {
    px_l[p] = xb[p * 3 + 0];
    py_l[p] = xb[p * 3 + 1];
    pz_l[p] = xb[p * 3 + 2];
  }
  __syncthreads();

  // register fill from LDS: thread owns pairs (2t+512j, 2t+512j+1)
  f2 pxv[16], pyv[16], pzv[16], mindv[16];
#pragma unroll
  for (int j = 0; j < 16; ++j) {
    int p = 2 * tid + 512 * j;
    pxv[j] = *(const f2*)&px_l[p];
    pyv[j] = *(const f2*)&py_l[p];
    pzv[j] = *(const f2*)&pz_l[p];
    mindv[j] = f2{1e10f, 1e10f};
  }
  float qx = px_l[0], qy = py_l[0], qz = pz_l[0];  // pivot = point 0

  for (int i = 1; i < NPOINT; ++i) {
#pragma clang fp contract(off)
    const int par = i & 1;
    f2 qx2 = f2{qx, qx}, qy2 = f2{qy, qy}, qz2 = f2{qz, qz};

    // distance update (exact ref order) + value-only max tree
    f2 tmax;
#pragma unroll
    for (int j = 0; j < 16; ++j) {
      f2 dx = pxv[j] - qx2;
      f2 dy = pyv[j] - qy2;
      f2 dz = pzv[j] - qz2;
      f2 d = (dx * dx + dy * dy) + dz * dz;
      f2 m = __builtin_elementwise_min(mindv[j], d);
      mindv[j] = m;
      tmax = (j == 0) ? m : __builtin_elementwise_max(tmax, m);
    }
    float lmax = fmaxf(tmax.x, tmax.y);

    // thread-local lowest global index achieving lmax
    // global idx = 2*tid + 512*j + k; scan j desc, y(k=1) then x(k=0)
    int c = 0;
#pragma unroll
    for (int j = 15; j >= 0; --j) {
      if (mindv[j].y == lmax) c = 2 * j + 1;
      if (mindv[j].x == lmax) c = 2 * j;
    }
    unsigned int gidx = (unsigned int)(2 * tid + ((c >> 1) << 9) + (c & 1));
    unsigned long long key =
        ((unsigned long long)__float_as_uint(lmax) << 32) |
        (unsigned long long)(~gidx);

    // wave argmax via DPP (VALU-speed), result valid in lane 63
    key = dpp_max_u64<0x111>(key);  // row_shr:1
    key = dpp_max_u64<0x112>(key);  // row_shr:2
    key = dpp_max_u64<0x114>(key);  // row_shr:4
    key = dpp_max_u64<0x118>(key);  // row_shr:8
    key = dpp_max_u64<0x142>(key);  // row_bcast:15
    key = dpp_max_u64<0x143>(key);  // row_bcast:31

    if (lane == 63) pk2[par][wid] = key;  // 8B only
    __syncthreads();

    // merge 4 keys: 2x ds_read_b128 + 3 u64 compare-selects
    ulonglong2 k01 = *(const ulonglong2*)&pk2[par][0];
    ulonglong2 k23 = *(const ulonglong2*)&pk2[par][2];
    unsigned long long m01 = (k01.x > k01.y) ? k01.x : k01.y;
    unsigned long long m23 = (k23.x > k23.y) ? k23.x : k23.y;
    unsigned long long mk = (m01 > m23) ? m01 : m23;
    unsigned int widx = ~(unsigned int)mk;  // identical on every thread

    // pivot coords: broadcast ds_read at the winner (post-merge, parallel)
    qx = px_l[widx];
    qy = py_l[widx];
    qz = pz_l[widx];
    if (tid == 0) winidx[i] = (unsigned short)widx;
  }

  __syncthreads();
  // write all 1024 sampled points from LDS
  for (int t = tid; t < NPOINT; t += 256) {
    const int idx = (t == 0) ? 0 : (int)winidx[t];
    float* op = newxyz + b * (NPOINT * 3) + t * 3;
    op[0] = px_l[idx];
    op[1] = py_l[idx];
    op[2] = pz_l[idx];
  }
}

// ---------------------------------------------------------------------------
// Ball query: one wave per (b, s) center. Unchanged (exact fp32).
// ---------------------------------------------------------------------------
__global__ __launch_bounds__(256) void ball_kernel(const float* __restrict__ xyz,
                                                   const float* __restrict__ newxyz,
                                                   int* __restrict__ idxout) {
  const int lane = threadIdx.x & 63;
  const int pair = blockIdx.x * 4 + (threadIdx.x >> 6);
  const int b = pair >> 10;
  const float cx = newxyz[pair * 3 + 0];
  const float cy = newxyz[pair * 3 + 1];
  const float cz = newxyz[pair * 3 + 2];
  const float* xb = xyz + (size_t)b * NPTS * 3;
  int* op = idxout + pair * NSAMPLE;

  int cnt = 0;
  int first = 0;
  for (int base = 0; base < NPTS && cnt < NSAMPLE; base += 64) {
    const int p = base + lane;
    const float* pp = xb + p * 3;
    float dx = __fsub_rn(cx, pp[0]);
    float dy = __fsub_rn(cy, pp[1]);
    float dz = __fsub_rn(cz, pp[2]);
    float d2 = __fadd_rn(__fadd_rn(__fmul_rn(dx, dx), __fmul_rn(dy, dy)),
                         __fmul_rn(dz, dz));
    bool pred = d2 < 0.04f;
    unsigned long long m = __ballot(pred);
    if (cnt == 0 && m) first = base + __builtin_ctzll(m);
    int rank = cnt + (int)__popcll(m & ((1ull << lane) - 1ull));
    if (pred && rank < NSAMPLE) op[rank] = p;
    cnt += (int)__popcll(m);
  }
  if (cnt < NSAMPLE) {
    for (int r = cnt + lane; r < NSAMPLE; r += 64) op[r] = first;
  }
}

// ---------------------------------------------------------------------------
// Group + 3-layer MLP + max-pool via f16 MFMA. G=16 groups/block, grid 512.
// Unchanged from R10 (weights register-resident as B-fragments, layouts
// HW-verified m89/m120, fp32 accumulate; absmax 0.0156 < 0.054).
// ---------------------------------------------------------------------------
__global__ __launch_bounds__(256) void group_mlp_kernel(
    const float* __restrict__ xyz, const float* __restrict__ feat,
    const float* __restrict__ w0, const float* __restrict__ s0, const float* __restrict__ b0,
    const float* __restrict__ w1, const float* __restrict__ s1, const float* __restrict__ b1,
    const float* __restrict__ w2, const float* __restrict__ s2, const float* __restrict__ b2,
    const int* __restrict__ idxin, const float* __restrict__ newxyz,
    float* __restrict__ outf) {
  __shared__ _Float16 x0[32 * 104];  // layer1 input, K-padded to 96
  __shared__ _Float16 x1[32 * 72];   // layer2 input
  __shared__ _Float16 x2[32 * 72];   // layer3 input
  __shared__ float obuf[128 * G];

  const int tid = threadIdx.x;
  const int lane = tid & 63;
  const int wv = tid >> 6;       // wave 0..3
  const int qd = lane >> 4;      // quad 0..3
  const int col = lane & 15;
  const int pair0 = blockIdx.x * G;
  const int b = pair0 >> 10;
  const int sbase = pair0 & 1023;

  // ---- build register-resident B-fragments (once per block) ----
  h8 bf1[3], bf2[2], bf3[2][2];
  {
    const int o1 = wv * 16 + col;  // L1/L2 channel for this lane
#pragma unroll
    for (int t = 0; t < 3; ++t) {
#pragma unroll
      for (int j = 0; j < 8; ++j) {
        int kp = t * 32 + qd * 8 + j;  // permuted K index
        float v = 0.f;
        if (kp < 64) v = w0[o1 * 67 + 3 + kp];
        else if (kp < 67) v = w0[o1 * 67 + (kp - 64)];
        bf1[t][j] = (_Float16)v;
      }
    }
#pragma unroll
    for (int t = 0; t < 2; ++t) {
#pragma unroll
      for (int j = 0; j < 8; ++j) {
        int k = t * 32 + qd * 8 + j;
        bf2[t][j] = (_Float16)w1[o1 * 64 + k];
      }
    }
#pragma unroll
    for (int u = 0; u < 2; ++u) {
      const int o3 = (wv + 4 * u) * 16 + col;
#pragma unroll
      for (int t = 0; t < 2; ++t) {
#pragma unroll
        for (int j = 0; j < 8; ++j) {
          int k = t * 32 + qd * 8 + j;
          bf3[u][t][j] = (_Float16)w2[o3 * 64 + k];
        }
      }
    }
  }
  const int o12 = wv * 16 + col;
  const float sA = s0[o12], bA = b0[o12];
  const float sB = s1[o12], bB = b1[o12];
  const float sC0 = s2[o12], bC0 = b2[o12];
  const float sC1 = s2[o12 + 64], bC1 = b2[o12 + 64];

  for (int t = tid; t < 32 * 40; t += 256) {
    x0[(t / 40) * 104 + 64 + (t % 40)] = (_Float16)0.f;
  }

  const int gn = tid >> 3, gk = tid & 7;

  f4 pf0, pf1;
  float pxr = 0.f, pyr = 0.f, pzr = 0.f, cxr = 0.f, cyr = 0.f, czr = 0.f;
  {
    const int pid = idxin[pair0 * NSAMPLE + gn];
    const float* fr = feat + ((size_t)(b * NPTS) + pid) * NCH + gk * 8;
    pf0 = *(const f4*)fr;
    pf1 = *(const f4*)(fr + 4);
    if (gk == 0) {
      const float* pr = xyz + ((size_t)(b * NPTS) + pid) * 3;
      pxr = pr[0]; pyr = pr[1]; pzr = pr[2];
      cxr = newxyz[pair0 * 3 + 0];
      cyr = newxyz[pair0 * 3 + 1];
      czr = newxyz[pair0 * 3 + 2];
    }
  }

  for (int g = 0; g < G; ++g) {
    {
      h8 hv;
#pragma unroll
      for (int q = 0; q < 4; ++q) {
        hv[q] = (_Float16)pf0[q];
        hv[4 + q] = (_Float16)pf1[q];
      }
      *(h8*)&x0[gn * 104 + gk * 8] = hv;
      if (gk == 0) {
        x0[gn * 104 + 64] = (_Float16)(pxr - cxr);
        x0[gn * 104 + 65] = (_Float16)(pyr - cyr);
        x0[gn * 104 + 66] = (_Float16)(pzr - czr);
      }
    }
    __syncthreads();  // bar A: x0 ready

    if (g + 1 < G) {
      const int pairg = pair0 + g + 1;
      const int pid = idxin[pairg * NSAMPLE + gn];
      const float* fr = feat + ((size_t)(b * NPTS) + pid) * NCH + gk * 8;
      pf0 = *(const f4*)fr;
      pf1 = *(const f4*)(fr + 4);
      if (gk == 0) {
        const float* pr = xyz + ((size_t)(b * NPTS) + pid) * 3;
        pxr = pr[0]; pyr = pr[1]; pzr = pr[2];
        cxr = newxyz[pairg * 3 + 0];
        cyr = newxyz[pairg * 3 + 1];
        czr = newxyz[pairg * 3 + 2];
      }
    }

    // ---- layer 1 ----
    {
      f4 a0 = {0.f, 0.f, 0.f, 0.f}, a1 = a0;
#pragma unroll
      for (int t = 0; t < 3; ++t) {
        h8 fa0 = *(const h8*)&x0[col * 104 + t * 32 + qd * 8];
        h8 fa1 = *(const h8*)&x0[(16 + col) * 104 + t * 32 + qd * 8];
        a0 = __builtin_amdgcn_mfma_f32_16x16x32_f16(fa0, bf1[t], a0, 0, 0, 0);
        a1 = __builtin_amdgcn_mfma_f32_16x16x32_f16(fa1, bf1[t], a1, 0, 0, 0);
      }
#pragma unroll
      for (int r = 0; r < 4; ++r) {
        float v0 = fmaxf(fmaf(a0[r], sA, bA), 0.f);
        float v1 = fmaxf(fmaf(a1[r], sA, bA), 0.f);
        x1[(qd * 4 + r) * 72 + o12] = (_Float16)v0;
        x1[(16 + qd * 4 + r) * 72 + o12] = (_Float16)v1;
      }
    }
    __syncthreads();  // bar B: x1 ready

    // ---- layer 2 ----
    {
      f4 a0 = {0.f, 0.f, 0.f, 0.f}, a1 = a0;
#pragma unroll
      for (int t = 0; t < 2; ++t) {
        h8 fa0 = *(const h8*)&x1[col * 72 + t * 32 + qd * 8];
        h8 fa1 = *(const h8*)&x1[(16 + col) * 72 + t * 32 + qd * 8];
        a0 = __builtin_amdgcn_mfma_f32_16x16x32_f16(fa0, bf2[t], a0, 0, 0, 0);
        a1 = __builtin_amdgcn_mfma_f32_16x16x32_f16(fa1, bf2[t], a1, 0, 0, 0);
      }
#pragma unroll
      for (int r = 0; r < 4; ++r) {
        float v0 = fmaxf(fmaf(a0[r], sB, bB), 0.f);
        float v1 = fmaxf(fmaf(a1[r], sB, bB), 0.f);
        x2[(qd * 4 + r) * 72 + o12] = (_Float16)v0;
        x2[(16 + qd * 4 + r) * 72 + o12] = (_Float16)v1;
      }
    }
    __syncthreads();  // bar C: x2 ready

    // ---- layer 3 + max-pool ----
    {
      f4 c00 = {0.f, 0.f, 0.f, 0.f}, c01 = c00, c10 = c00, c11 = c00;
#pragma unroll
      for (int t = 0; t < 2; ++t) {
        h8 fa0 = *(const h8*)&x2[col * 72 + t * 32 + qd * 8];
        h8 fa1 = *(const h8*)&x2[(16 + col) * 72 + t * 32 + qd * 8];
        c00 = __builtin_amdgcn_mfma_f32_16x16x32_f16(fa0, bf3[0][t], c00, 0, 0, 0);
        c01 = __builtin_amdgcn_mfma_f32_16x16x32_f16(fa1, bf3[0][t], c01, 0, 0, 0);
        c10 = __builtin_amdgcn_mfma_f32_16x16x32_f16(fa0, bf3[1][t], c10, 0, 0, 0);
        c11 = __builtin_amdgcn_mfma_f32_16x16x32_f16(fa1, bf3[1][t], c11, 0, 0, 0);
      }
      float mx0 = 0.f, mx1 = 0.f;  // relu output >= 0
#pragma unroll
      for (int r = 0; r < 4; ++r) {
        mx0 = fmaxf(mx0, fmaxf(fmaf(c00[r], sC0, bC0), 0.f));
        mx0 = fmaxf(mx0, fmaxf(fmaf(c01[r], sC0, bC0), 0.f));
        mx1 = fmaxf(mx1, fmaxf(fmaf(c10[r], sC1, bC1), 0.f));
        mx1 = fmaxf(mx1, fmaxf(fmaf(c11[r], sC1, bC1), 0.f));
      }
      mx0 = fmaxf(mx0, __shfl_xor(mx0, 16));
      mx0 = fmaxf(mx0, __shfl_xor(mx0, 32));
      mx1 = fmaxf(mx1, __shfl_xor(mx1, 16));
      mx1 = fmaxf(mx1, __shfl_xor(mx1, 32));
      if (lane < 16) {
        obuf[o12 * G + g] = mx0;
        obuf[(o12 + 64) * G + g] = mx1;
      }
    }
  }

  __syncthreads();
  {
    const int ch = tid >> 1, hb = (tid & 1) * 8;
    f4 v0 = *(const f4*)&obuf[ch * G + hb];
    f4 v1 = *(const f4*)&obuf[ch * G + hb + 4];
    float* dst = &outf[((size_t)(b * 128 + ch)) * 1024 + sbase + hb];
    *(f4*)dst = v0;
    *(f4*)(dst + 4) = v1;
  }
}

extern "C" void kernel_launch(void* const* d_in, const int* in_sizes, int n_in,
                              void* d_out, int out_size, void* d_ws, size_t ws_size,
                              hipStream_t stream) {
  const float* xyz = (const float*)d_in[0];
  const float* feat = (const float*)d_in[1];
  const float* w0 = (const float*)d_in[2];
  const float* s0 = (const float*)d_in[3];
  const float* b0 = (const float*)d_in[4];
  const float* w1 = (const float*)d_in[5];
  const float* s1 = (const float*)d_in[6];
  const float* b1 = (const float*)d_in[7];
  const float* w2 = (const float*)d_in[8];
  const float* s2 = (const float*)d_in[9];
  const float* b2 = (const float*)d_in[10];

  float* newxyz = (float*)d_out;                    // (8,1024,3)
  float* outf = (float*)d_out + BATCH * NPOINT * 3; // (8,128,1024)
  int* idxws = (int*)d_ws;                          // (8*1024, 32) ints = 1 MB

  fps_kernel<<<BATCH, 256, 0, stream>>>(xyz, newxyz);
  ball_kernel<<<(BATCH * NPOINT) / 4, 256, 0, stream>>>(xyz, newxyz, idxws);
  group_mlp_kernel<<<(BATCH * NPOINT) / G, 256, 0, stream>>>(
      xyz, feat, w0, s0, b0, w1, s1, b1, w2, s2, b2, idxws, newxyz, outf);
}